// Round 3
// baseline (103.781 us; speedup 1.0000x reference)
//
#include <hip/hip_runtime.h>
#include <math.h>

#define N_CAM 6
#define C_IN 256
#define C_OUT 80
#define FH 32
#define FW 88
#define NXG 200
#define NYG 200
#define S_SPATIAL (NXG*NYG)        // 40000
#define POS_PER_CAM (FH*FW)        // 2816
#define NPOS (N_CAM*POS_PER_CAM)   // 16896

// ws layout (in floats)
#define WS_PA    0      // 84 floats: proj[6][12] + aug[6][2]
#define WS_BIAS  128    // 80 floats
#define WS_W2N   256    // w2n[o][c]: 80*256 = 20480 floats
#define WS_FEAT2 20736  // NPOS*80 = 1,351,680 floats (~5.4 MB)

// ---------------- kernel 1: projection matrices + BN-folded weights ----------------
__global__ void k_prep(const float* __restrict__ iam,
                       const float* __restrict__ lam,
                       const float* __restrict__ l2i,
                       const float* __restrict__ conv_w, const float* __restrict__ conv_b,
                       const float* __restrict__ gamma, const float* __restrict__ beta,
                       const float* __restrict__ mean, const float* __restrict__ var,
                       float* __restrict__ pa, float* __restrict__ w2n,
                       float* __restrict__ bias2) {
    int bid = blockIdx.x;
    int t = threadIdx.x;
    if (bid == 0) {
        if (t >= N_CAM) return;
        int n = t;
        const float* A = iam + n * 16;   // img_aug_matrix (last col zeroed for proj)
        const float* L = l2i + n * 16;   // lidar2image
        float M1[12];
        #pragma unroll
        for (int i = 0; i < 3; ++i) {
            #pragma unroll
            for (int j = 0; j < 4; ++j) {
                float acc = __fmul_rn(A[i*4+0], L[0*4+j]);
                acc = __fmaf_rn(A[i*4+1], L[1*4+j], acc);
                acc = __fmaf_rn(A[i*4+2], L[2*4+j], acc);
                M1[i*4+j] = acc;
            }
        }
        #pragma unroll
        for (int i = 0; i < 3; ++i) {
            #pragma unroll
            for (int j = 0; j < 4; ++j) {
                float acc = __fmul_rn(M1[i*4+0], lam[0*4+j]);
                acc = __fmaf_rn(M1[i*4+1], lam[1*4+j], acc);
                acc = __fmaf_rn(M1[i*4+2], lam[2*4+j], acc);
                acc = __fmaf_rn(M1[i*4+3], lam[3*4+j], acc);
                pa[n*12 + i*4 + j] = acc;
            }
        }
        pa[72 + n*2 + 0] = A[0*4 + 3];
        pa[72 + n*2 + 1] = A[1*4 + 3];
    } else {
        // fold BN into conv weights, row-major per output: w2n[o*256 + c]
        int o = bid - 1;                 // 0..79
        float inv = 1.0f / sqrtf(var[o] + 1e-5f);
        float sc = __fmul_rn(inv, gamma[o]);
        w2n[o * C_IN + t] = __fmul_rn(conv_w[o * C_IN + t], sc);
        if (t == 0) {
            bias2[o] = __fadd_rn(__fmul_rn(__fsub_rn(conv_b[o], mean[o]), sc), beta[o]);
        }
    }
}

// ---------------- kernel 2: feat2[pos][o] = sum_c w2[o][c]*feat[c][pos] ----------------
// 264 blocks x 256 threads; block tile = 64 pos x 80 out; thread = 4 pos x 5 out.
#define CK 32
__global__ __launch_bounds__(256) void k_conv(const float* __restrict__ feat,
                                              const float* __restrict__ w2n,
                                              float* __restrict__ feat2) {
    __shared__ float ftile[2][CK][64];       // 16 KiB
    __shared__ float wtile[2][C_OUT][36];    // 22.5 KiB (stride 36: 16B-aligned rows)
    __shared__ float s_out[64][81];          // 20.25 KiB epilogue transpose
    int b = blockIdx.x;                      // 264 = 6 cams * 44 tiles
    int n = b / 44;
    int vu0 = (b % 44) * 64;
    int t = threadIdx.x;
    int pg = t & 15;                         // positions pg*4 .. pg*4+3
    int og = t >> 4;                         // outputs og*5 .. og*5+4
    const float* feat_n = feat + (size_t)n * C_IN * POS_PER_CAM + vu0;

    float acc[4][5];
    #pragma unroll
    for (int p = 0; p < 4; ++p)
        #pragma unroll
        for (int k = 0; k < 5; ++k) acc[p][k] = 0.0f;

    // addressing for staging
    int f0 = t,        fcc0 = f0 >> 4, fp0 = (f0 & 15) << 2;
    int f1 = 256 + t,  fcc1 = f1 >> 4, fp1 = (f1 & 15) << 2;
    int w0 = t,        wo0 = w0 >> 3, wc0 = (w0 & 7) << 2;
    int w1 = 256 + t,  wo1 = w1 >> 3, wc1 = (w1 & 7) << 2;
    int w2i = 512 + t, wo2 = w2i >> 3, wc2 = (w2i & 7) << 2;   // only t < 128

    // prologue: stage chunk 0
    {
        *reinterpret_cast<float4*>(&ftile[0][fcc0][fp0]) =
            *reinterpret_cast<const float4*>(feat_n + (size_t)fcc0 * POS_PER_CAM + fp0);
        *reinterpret_cast<float4*>(&ftile[0][fcc1][fp1]) =
            *reinterpret_cast<const float4*>(feat_n + (size_t)fcc1 * POS_PER_CAM + fp1);
        *reinterpret_cast<float4*>(&wtile[0][wo0][wc0]) =
            *reinterpret_cast<const float4*>(w2n + wo0 * C_IN + wc0);
        *reinterpret_cast<float4*>(&wtile[0][wo1][wc1]) =
            *reinterpret_cast<const float4*>(w2n + wo1 * C_IN + wc1);
        if (t < 128)
            *reinterpret_cast<float4*>(&wtile[0][wo2][wc2]) =
                *reinterpret_cast<const float4*>(w2n + wo2 * C_IN + wc2);
    }
    __syncthreads();

    #pragma unroll 2
    for (int chunk = 0; chunk < 8; ++chunk) {
        int cb = chunk & 1;
        // T14: issue next chunk's global loads now, write to LDS after compute
        float4 pf0, pf1, pw0, pw1, pw2;
        if (chunk < 7) {
            int c1 = (chunk + 1) * CK;
            pf0 = *reinterpret_cast<const float4*>(feat_n + (size_t)(c1 + fcc0) * POS_PER_CAM + fp0);
            pf1 = *reinterpret_cast<const float4*>(feat_n + (size_t)(c1 + fcc1) * POS_PER_CAM + fp1);
            pw0 = *reinterpret_cast<const float4*>(w2n + wo0 * C_IN + c1 + wc0);
            pw1 = *reinterpret_cast<const float4*>(w2n + wo1 * C_IN + c1 + wc1);
            if (t < 128)
                pw2 = *reinterpret_cast<const float4*>(w2n + wo2 * C_IN + c1 + wc2);
        }
        // compute: per 4-channel step: 4 pos b128 + 5 weight b128 -> 80 FMA
        #pragma unroll
        for (int q = 0; q < CK/4; ++q) {
            float4 fp[4], wv[5];
            #pragma unroll
            for (int j = 0; j < 4; ++j)
                fp[j] = *reinterpret_cast<const float4*>(&ftile[cb][q*4+j][pg*4]);
            #pragma unroll
            for (int k = 0; k < 5; ++k)
                wv[k] = *reinterpret_cast<const float4*>(&wtile[cb][og*5+k][q*4]);
            #pragma unroll
            for (int j = 0; j < 4; ++j) {          // channel ascending (matches np order)
                #pragma unroll
                for (int k = 0; k < 5; ++k) {
                    float w = (&wv[k].x)[j];
                    acc[0][k] = __fmaf_rn(w, (&fp[j].x)[0], acc[0][k]);
                    acc[1][k] = __fmaf_rn(w, (&fp[j].x)[1], acc[1][k]);
                    acc[2][k] = __fmaf_rn(w, (&fp[j].x)[2], acc[2][k]);
                    acc[3][k] = __fmaf_rn(w, (&fp[j].x)[3], acc[3][k]);
                }
            }
        }
        // write prefetched chunk into the other buffer
        if (chunk < 7) {
            int nb = cb ^ 1;
            *reinterpret_cast<float4*>(&ftile[nb][fcc0][fp0]) = pf0;
            *reinterpret_cast<float4*>(&ftile[nb][fcc1][fp1]) = pf1;
            *reinterpret_cast<float4*>(&wtile[nb][wo0][wc0]) = pw0;
            *reinterpret_cast<float4*>(&wtile[nb][wo1][wc1]) = pw1;
            if (t < 128)
                *reinterpret_cast<float4*>(&wtile[nb][wo2][wc2]) = pw2;
        }
        __syncthreads();
    }

    // epilogue: transpose via LDS, then coalesced global stores
    #pragma unroll
    for (int p = 0; p < 4; ++p)
        #pragma unroll
        for (int k = 0; k < 5; ++k)
            s_out[pg*4 + p][og*5 + k] = acc[p][k];
    __syncthreads();
    float* gdst = feat2 + ((size_t)n * POS_PER_CAM + vu0) * C_OUT;
    #pragma unroll
    for (int it = 0; it < 20; ++it) {
        int f = it * 256 + t;                // 5120 floats
        int pos = f / 80, o = f - pos * 80;
        gdst[f] = s_out[pos][o];
    }
}

// ---------------- kernel 3: backproject + weighted z-sum + bias + relu ----------------
__global__ __launch_bounds__(256) void k_main(const float* __restrict__ feat2,
                                              const float* __restrict__ pa_g,
                                              const float* __restrict__ bias_g,
                                              const float* __restrict__ points,
                                              float* __restrict__ out) {
    __shared__ float s_pa[84];
    __shared__ float s_bias[C_OUT];
    __shared__ int   s_base[64];
    __shared__ float s_w[64];
    __shared__ float s_y[16 * 81];   // stride 81: conflict-free transpose
    int t = threadIdx.x;
    int col0 = blockIdx.x * 16;

    if (t < 84) s_pa[t] = pa_g[t];
    else if (t >= 128 && t < 128 + C_OUT) s_bias[t - 128] = bias_g[t - 128];
    __syncthreads();

    // phase 1: per (column, z) camera selection — fp32 mimicking numpy op order
    if (t < 64) {
        int cl = t >> 2, z = t & 3;
        int col = col0 + cl;
        int ix = col / NYG, iy = col % NYG;
        float x  = (float)ix * 0.5f - 50.0f;   // exact dyadic
        float y  = (float)iy * 0.5f - 50.0f;
        float zc = (float)z  * 1.5f - 4.0f;
        int sel_base = 0;
        bool any = false;
        #pragma unroll
        for (int n = 0; n < N_CAM; ++n) {
            const float* P = s_pa + n * 12;
            // sequential non-fused mul/add: matches np.einsum (no FMA, j ascending)
            float px = __fadd_rn(__fadd_rn(__fadd_rn(__fmul_rn(P[0], x), __fmul_rn(P[1], y)), __fmul_rn(P[2], zc)), P[3]);
            float py = __fadd_rn(__fadd_rn(__fadd_rn(__fmul_rn(P[4], x), __fmul_rn(P[5], y)), __fmul_rn(P[6], zc)), P[7]);
            float pz = __fadd_rn(__fadd_rn(__fadd_rn(__fmul_rn(P[8], x), __fmul_rn(P[9], y)), __fmul_rn(P[10], zc)), P[11]);
            float Z = pz;
            float Zs = (fabsf(Z) > 1e-6f) ? Z : 1e-6f;
            float u = __fadd_rn(px / Zs, s_pa[72 + n*2 + 0]);
            float v = __fadd_rn(py / Zs, s_pa[72 + n*2 + 1]);
            float uf = rintf(__fmul_rn(u, 0.125f));   // u/8 exact; rintf = half-even = np.round
            float vf = rintf(__fmul_rn(v, 0.125f));
            int ui = (int)uf, vi = (int)vf;           // saturating cvt; out-of-range stays invalid
            bool val = (ui >= 0) & (vi >= 0) & (ui < FW) & (vi < FH) & (Z > 0.0f);
            if (val) { sel_base = ((n * FH + vi) * FW + ui) * C_OUT; any = true; }  // last valid wins
        }
        float w = 0.0f;
        if (any) w = points[z * S_SPATIAL + col];
        else sel_base = 0;
        s_base[t] = sel_base;
        s_w[t] = w;
    }
    __syncthreads();

    // phase 2: gather 80 contiguous floats per (col,z), weighted z-sum, bias, relu
    #pragma unroll
    for (int it = 0; it < 5; ++it) {
        int idx = it * 256 + t;            // 16 cols * 80 outs = 1280
        int cl = idx / 80, o = idx - cl * 80;
        float acc =            __fmul_rn(s_w[cl*4+0], feat2[s_base[cl*4+0] + o]);
        acc = __fadd_rn(acc, __fmul_rn(s_w[cl*4+1], feat2[s_base[cl*4+1] + o]));
        acc = __fadd_rn(acc, __fmul_rn(s_w[cl*4+2], feat2[s_base[cl*4+2] + o]));
        acc = __fadd_rn(acc, __fmul_rn(s_w[cl*4+3], feat2[s_base[cl*4+3] + o]));
        float yv = fmaxf(__fadd_rn(acc, s_bias[o]), 0.0f);
        s_y[cl * 81 + o] = yv;
    }
    __syncthreads();

    // phase 3: transposed write — coalesced 16-float segments per o
    #pragma unroll
    for (int it = 0; it < 5; ++it) {
        int idx = it * 256 + t;
        int o = idx >> 4, cl = idx & 15;
        out[o * S_SPATIAL + col0 + cl] = s_y[cl * 81 + o];
    }
}

extern "C" void kernel_launch(void* const* d_in, const int* in_sizes, int n_in,
                              void* d_out, int out_size, void* d_ws, size_t ws_size,
                              hipStream_t stream) {
    const float* feat   = (const float*)d_in[0];   // (1,6,256,32,88)
    const float* points = (const float*)d_in[1];   // (1,4,200,200)
    const float* l2i    = (const float*)d_in[5];   // lidar2image (1,6,4,4)
    const float* iam    = (const float*)d_in[8];   // img_aug_matrix (1,6,4,4)
    const float* lam    = (const float*)d_in[9];   // lidar_aug_matrix (1,4,4)
    const float* conv_w = (const float*)d_in[11];  // (80,256)
    const float* conv_b = (const float*)d_in[12];
    const float* gamma  = (const float*)d_in[13];
    const float* beta   = (const float*)d_in[14];
    const float* mean   = (const float*)d_in[15];
    const float* var    = (const float*)d_in[16];

    float* ws    = (float*)d_ws;
    float* pa    = ws + WS_PA;
    float* bias2 = ws + WS_BIAS;
    float* w2n   = ws + WS_W2N;
    float* feat2 = ws + WS_FEAT2;
    float* out   = (float*)d_out;

    hipLaunchKernelGGL(k_prep, dim3(1 + C_OUT), dim3(256), 0, stream,
                       iam, lam, l2i, conv_w, conv_b, gamma, beta, mean, var,
                       pa, w2n, bias2);
    hipLaunchKernelGGL(k_conv, dim3(NPOS / 64), dim3(256), 0, stream, feat, w2n, feat2);
    hipLaunchKernelGGL(k_main, dim3(S_SPATIAL / 16), dim3(256), 0, stream,
                       feat2, pa, bias2, points, out);
}

// Round 4
// 52.742 us; speedup vs baseline: 1.9677x; 1.9677x over previous
//
#include <hip/hip_runtime.h>
#include <math.h>

#define N_CAM 6
#define C_IN 256
#define C_OUT 80
#define FH 32
#define FW 88
#define NXG 200
#define NYG 200
#define S_SPATIAL (NXG*NYG)        // 40000
#define POS_PER_CAM (FH*FW)        // 2816
#define NPOS (N_CAM*POS_PER_CAM)   // 16896

// ws layout (in floats)
#define WS_PA    0      // 84 floats: proj[6][12] + aug[6][2]
#define WS_BIAS  128    // 80 floats
#define WS_W2N   256    // w2n[o][c]: 80*256 = 20480 floats
#define WS_FEAT2 20736  // NPOS*80 = 1,351,680 floats (~5.4 MB)

__device__ __forceinline__ void gload_lds16(const float* g, float* l) {
    __builtin_amdgcn_global_load_lds(
        (const __attribute__((address_space(1))) void*)g,
        (__attribute__((address_space(3))) void*)l, 16, 0, 0);
}

// ---------------- kernel 1: projection matrices + BN-folded weights ----------------
__global__ void k_prep(const float* __restrict__ iam,
                       const float* __restrict__ lam,
                       const float* __restrict__ l2i,
                       const float* __restrict__ conv_w, const float* __restrict__ conv_b,
                       const float* __restrict__ gamma, const float* __restrict__ beta,
                       const float* __restrict__ mean, const float* __restrict__ var,
                       float* __restrict__ pa, float* __restrict__ w2n,
                       float* __restrict__ bias2) {
    int bid = blockIdx.x;
    int t = threadIdx.x;
    if (bid == 0) {
        if (t >= N_CAM) return;
        int n = t;
        const float* A = iam + n * 16;   // img_aug_matrix (last col zeroed for proj)
        const float* L = l2i + n * 16;   // lidar2image
        float M1[12];
        #pragma unroll
        for (int i = 0; i < 3; ++i) {
            #pragma unroll
            for (int j = 0; j < 4; ++j) {
                float acc = __fmul_rn(A[i*4+0], L[0*4+j]);
                acc = __fmaf_rn(A[i*4+1], L[1*4+j], acc);
                acc = __fmaf_rn(A[i*4+2], L[2*4+j], acc);
                M1[i*4+j] = acc;
            }
        }
        #pragma unroll
        for (int i = 0; i < 3; ++i) {
            #pragma unroll
            for (int j = 0; j < 4; ++j) {
                float acc = __fmul_rn(M1[i*4+0], lam[0*4+j]);
                acc = __fmaf_rn(M1[i*4+1], lam[1*4+j], acc);
                acc = __fmaf_rn(M1[i*4+2], lam[2*4+j], acc);
                acc = __fmaf_rn(M1[i*4+3], lam[3*4+j], acc);
                pa[n*12 + i*4 + j] = acc;
            }
        }
        pa[72 + n*2 + 0] = A[0*4 + 3];
        pa[72 + n*2 + 1] = A[1*4 + 3];
    } else {
        // fold BN into conv weights, row-major per output: w2n[o*256 + c]
        int o = bid - 1;                 // 0..79
        float inv = 1.0f / sqrtf(var[o] + 1e-5f);
        float sc = __fmul_rn(inv, gamma[o]);
        w2n[o * C_IN + t] = __fmul_rn(conv_w[o * C_IN + t], sc);
        if (t == 0) {
            bias2[o] = __fadd_rn(__fmul_rn(__fsub_rn(conv_b[o], mean[o]), sc), beta[o]);
        }
    }
}

// ---------------- kernel 2: feat2[pos][o] = sum_c w2[o][c]*feat[c][pos] ----------------
// 264 blocks x 256 threads; block tile = 64 pos x 80 out; thread = 4 pos x 5 out.
// Weights: staged ONCE (83 KB LDS). feat: global_load_lds double-buffer, 2-phase.
#define CK 32
#define WPAD 260   // 16B-aligned rows; weight-read aliasing <= 2-way (free)
__global__ __launch_bounds__(256, 1) void k_conv(const float* __restrict__ feat,
                                                 const float* __restrict__ w2n,
                                                 float* __restrict__ feat2) {
    __shared__ float wtile[C_OUT][WPAD];     // 83.2 KiB, all 256 channels
    __shared__ float ftile[2][CK][64];       // 16 KiB double buffer (packed: gload_lds)
    __shared__ float s_out[64][81];          // 20.25 KiB epilogue transpose
    int b = blockIdx.x;                      // 264 = 6 cams * 44 tiles
    int n = b / 44;
    int vu0 = (b % 44) * 64;
    int t = threadIdx.x;
    int pg = t & 15;                         // positions pg*4 .. pg*4+3
    int og = t >> 4;                         // outputs og*5 .. og*5+4
    int w  = t >> 6;                         // wave id 0..3
    int lane = t & 63;
    const float* feat_n = feat + (size_t)n * C_IN * POS_PER_CAM + vu0;

    // ---- one-time weight stage: 80 rows x 256 ch, coalesced float4 ----
    #pragma unroll
    for (int it = 0; it < 20; ++it) {
        int idx = it * 256 + t;              // 5120 float4-chunks
        int r = idx >> 6, c4 = (idx & 63) << 2;
        *reinterpret_cast<float4*>(&wtile[r][c4]) =
            *reinterpret_cast<const float4*>(w2n + r * C_IN + c4);
    }

    // ---- feat staging addresses (global_load_lds: lane-linear LDS dest) ----
    // wave w, instr i in {0,1}: channels w*8+i*4 .. +3, lane -> (ch_sub=lane>>4, p4=(lane&15)*4)
    int ch_a = w * 8 + (lane >> 4);          // instr 0 channel (within chunk)
    int p4   = (lane & 15) << 2;
    const float* gsrc_a = feat_n + (size_t)ch_a * POS_PER_CAM + p4;
    const float* gsrc_b = gsrc_a + (size_t)4 * POS_PER_CAM;   // instr 1: ch+4

    // prologue: stage chunk 0 into buf 0
    gload_lds16(gsrc_a, &ftile[0][w * 8][0]);
    gload_lds16(gsrc_b, &ftile[0][w * 8 + 4][0]);
    __syncthreads();   // drains vmcnt+lgkmcnt, then barrier

    float acc[4][5];
    #pragma unroll
    for (int p = 0; p < 4; ++p)
        #pragma unroll
        for (int k = 0; k < 5; ++k) acc[p][k] = 0.0f;

    #pragma unroll 1
    for (int chunk = 0; chunk < C_IN / CK; ++chunk) {
        int cb = chunk & 1;
        // phase A: issue next chunk's loads into the other buffer (in flight under compute)
        if (chunk < C_IN / CK - 1) {
            const float* ga = gsrc_a + (size_t)(chunk + 1) * CK * POS_PER_CAM;
            const float* gb = gsrc_b + (size_t)(chunk + 1) * CK * POS_PER_CAM;
            gload_lds16(ga, &ftile[cb ^ 1][w * 8][0]);
            gload_lds16(gb, &ftile[cb ^ 1][w * 8 + 4][0]);
        }
        // phase B: compute current chunk; weights from resident wtile
        int c0 = chunk * CK;
        #pragma unroll
        for (int q = 0; q < CK / 4; ++q) {
            float4 fp[4], wv[5];
            #pragma unroll
            for (int j = 0; j < 4; ++j)
                fp[j] = *reinterpret_cast<const float4*>(&ftile[cb][q*4+j][pg*4]);
            #pragma unroll
            for (int k = 0; k < 5; ++k)
                wv[k] = *reinterpret_cast<const float4*>(&wtile[og*5+k][c0 + q*4]);
            #pragma unroll
            for (int j = 0; j < 4; ++j) {          // channel ascending (matches np order)
                #pragma unroll
                for (int k = 0; k < 5; ++k) {
                    float wgt = (&wv[k].x)[j];
                    acc[0][k] = __fmaf_rn(wgt, (&fp[j].x)[0], acc[0][k]);
                    acc[1][k] = __fmaf_rn(wgt, (&fp[j].x)[1], acc[1][k]);
                    acc[2][k] = __fmaf_rn(wgt, (&fp[j].x)[2], acc[2][k]);
                    acc[3][k] = __fmaf_rn(wgt, (&fp[j].x)[3], acc[3][k]);
                }
            }
        }
        __syncthreads();   // implicit vmcnt(0) drain -> next buffer ready for all waves
    }

    // epilogue: transpose via LDS, then coalesced global stores
    #pragma unroll
    for (int p = 0; p < 4; ++p)
        #pragma unroll
        for (int k = 0; k < 5; ++k)
            s_out[pg*4 + p][og*5 + k] = acc[p][k];
    __syncthreads();
    float* gdst = feat2 + ((size_t)n * POS_PER_CAM + vu0) * C_OUT;
    #pragma unroll
    for (int it = 0; it < 20; ++it) {
        int f = it * 256 + t;                // 5120 floats
        int pos = f / 80, o = f - pos * 80;
        gdst[f] = s_out[pos][o];
    }
}

// ---------------- kernel 3: backproject + weighted z-sum + bias + relu ----------------
__global__ __launch_bounds__(256) void k_main(const float* __restrict__ feat2,
                                              const float* __restrict__ pa_g,
                                              const float* __restrict__ bias_g,
                                              const float* __restrict__ points,
                                              float* __restrict__ out) {
    __shared__ float s_pa[84];
    __shared__ float s_bias[C_OUT];
    __shared__ int   s_base[64];
    __shared__ float s_w[64];
    __shared__ float s_y[16 * 81];   // stride 81: conflict-free transpose
    int t = threadIdx.x;
    int col0 = blockIdx.x * 16;

    if (t < 84) s_pa[t] = pa_g[t];
    else if (t >= 128 && t < 128 + C_OUT) s_bias[t - 128] = bias_g[t - 128];
    __syncthreads();

    // phase 1: per (column, z) camera selection — fp32 mimicking numpy op order
    if (t < 64) {
        int cl = t >> 2, z = t & 3;
        int col = col0 + cl;
        int ix = col / NYG, iy = col % NYG;
        float x  = (float)ix * 0.5f - 50.0f;   // exact dyadic
        float y  = (float)iy * 0.5f - 50.0f;
        float zc = (float)z  * 1.5f - 4.0f;
        int sel_base = 0;
        bool any = false;
        #pragma unroll
        for (int n = 0; n < N_CAM; ++n) {
            const float* P = s_pa + n * 12;
            // sequential non-fused mul/add: matches np.einsum (no FMA, j ascending)
            float px = __fadd_rn(__fadd_rn(__fadd_rn(__fmul_rn(P[0], x), __fmul_rn(P[1], y)), __fmul_rn(P[2], zc)), P[3]);
            float py = __fadd_rn(__fadd_rn(__fadd_rn(__fmul_rn(P[4], x), __fmul_rn(P[5], y)), __fmul_rn(P[6], zc)), P[7]);
            float pz = __fadd_rn(__fadd_rn(__fadd_rn(__fmul_rn(P[8], x), __fmul_rn(P[9], y)), __fmul_rn(P[10], zc)), P[11]);
            float Z = pz;
            float Zs = (fabsf(Z) > 1e-6f) ? Z : 1e-6f;
            float u = __fadd_rn(px / Zs, s_pa[72 + n*2 + 0]);
            float v = __fadd_rn(py / Zs, s_pa[72 + n*2 + 1]);
            float uf = rintf(__fmul_rn(u, 0.125f));   // u/8 exact; rintf = half-even = np.round
            float vf = rintf(__fmul_rn(v, 0.125f));
            int ui = (int)uf, vi = (int)vf;           // saturating cvt; out-of-range stays invalid
            bool val = (ui >= 0) & (vi >= 0) & (ui < FW) & (vi < FH) & (Z > 0.0f);
            if (val) { sel_base = ((n * FH + vi) * FW + ui) * C_OUT; any = true; }  // last valid wins
        }
        float w = 0.0f;
        if (any) w = points[z * S_SPATIAL + col];
        else sel_base = 0;
        s_base[t] = sel_base;
        s_w[t] = w;
    }
    __syncthreads();

    // phase 2: gather 80 contiguous floats per (col,z), weighted z-sum, bias, relu
    #pragma unroll
    for (int it = 0; it < 5; ++it) {
        int idx = it * 256 + t;            // 16 cols * 80 outs = 1280
        int cl = idx / 80, o = idx - cl * 80;
        float acc =            __fmul_rn(s_w[cl*4+0], feat2[s_base[cl*4+0] + o]);
        acc = __fadd_rn(acc, __fmul_rn(s_w[cl*4+1], feat2[s_base[cl*4+1] + o]));
        acc = __fadd_rn(acc, __fmul_rn(s_w[cl*4+2], feat2[s_base[cl*4+2] + o]));
        acc = __fadd_rn(acc, __fmul_rn(s_w[cl*4+3], feat2[s_base[cl*4+3] + o]));
        float yv = fmaxf(__fadd_rn(acc, s_bias[o]), 0.0f);
        s_y[cl * 81 + o] = yv;
    }
    __syncthreads();

    // phase 3: transposed write — coalesced 16-float segments per o
    #pragma unroll
    for (int it = 0; it < 5; ++it) {
        int idx = it * 256 + t;
        int o = idx >> 4, cl = idx & 15;
        out[o * S_SPATIAL + col0 + cl] = s_y[cl * 81 + o];
    }
}

extern "C" void kernel_launch(void* const* d_in, const int* in_sizes, int n_in,
                              void* d_out, int out_size, void* d_ws, size_t ws_size,
                              hipStream_t stream) {
    const float* feat   = (const float*)d_in[0];   // (1,6,256,32,88)
    const float* points = (const float*)d_in[1];   // (1,4,200,200)
    const float* l2i    = (const float*)d_in[5];   // lidar2image (1,6,4,4)
    const float* iam    = (const float*)d_in[8];   // img_aug_matrix (1,6,4,4)
    const float* lam    = (const float*)d_in[9];   // lidar_aug_matrix (1,4,4)
    const float* conv_w = (const float*)d_in[11];  // (80,256)
    const float* conv_b = (const float*)d_in[12];
    const float* gamma  = (const float*)d_in[13];
    const float* beta   = (const float*)d_in[14];
    const float* mean   = (const float*)d_in[15];
    const float* var    = (const float*)d_in[16];

    float* ws    = (float*)d_ws;
    float* pa    = ws + WS_PA;
    float* bias2 = ws + WS_BIAS;
    float* w2n   = ws + WS_W2N;
    float* feat2 = ws + WS_FEAT2;
    float* out   = (float*)d_out;

    hipLaunchKernelGGL(k_prep, dim3(1 + C_OUT), dim3(256), 0, stream,
                       iam, lam, l2i, conv_w, conv_b, gamma, beta, mean, var,
                       pa, w2n, bias2);
    hipLaunchKernelGGL(k_conv, dim3(NPOS / 64), dim3(256), 0, stream, feat, w2n, feat2);
    hipLaunchKernelGGL(k_main, dim3(S_SPATIAL / 16), dim3(256), 0, stream,
                       feat2, pa, bias2, points, out);
}

// Round 5
// 44.220 us; speedup vs baseline: 2.3469x; 1.1927x over previous
//
#include <hip/hip_runtime.h>
#include <math.h>

#define N_CAM 6
#define C_IN 256
#define C_OUT 80
#define FH 32
#define FW 88
#define NXG 200
#define NYG 200
#define S_SPATIAL (NXG*NYG)        // 40000
#define POS_PER_CAM (FH*FW)        // 2816
#define NPOS (N_CAM*POS_PER_CAM)   // 16896

// ws layout (in floats)
#define WS_PA    0      // 84 floats: proj[6][12] + aug[6][2]
#define WS_BIAS  128    // 80 floats
#define WS_W2N   256    // w2n[o][c]: 80*256 = 20480 floats
#define WS_FEAT2 20736  // NPOS*80 = 1,351,680 floats (~5.4 MB)

__device__ __forceinline__ void gload_lds16(const float* g, float* l) {
    __builtin_amdgcn_global_load_lds(
        (const __attribute__((address_space(1))) void*)g,
        (__attribute__((address_space(3))) void*)l, 16, 0, 0);
}

// ---------------- kernel 1: projection matrices + BN-folded weights ----------------
__global__ void k_prep(const float* __restrict__ iam,
                       const float* __restrict__ lam,
                       const float* __restrict__ l2i,
                       const float* __restrict__ conv_w, const float* __restrict__ conv_b,
                       const float* __restrict__ gamma, const float* __restrict__ beta,
                       const float* __restrict__ mean, const float* __restrict__ var,
                       float* __restrict__ pa, float* __restrict__ w2n,
                       float* __restrict__ bias2) {
    int bid = blockIdx.x;
    int t = threadIdx.x;
    if (bid == 0) {
        if (t >= N_CAM) return;
        int n = t;
        const float* A = iam + n * 16;   // img_aug_matrix (last col zeroed for proj)
        const float* L = l2i + n * 16;   // lidar2image
        float M1[12];
        #pragma unroll
        for (int i = 0; i < 3; ++i) {
            #pragma unroll
            for (int j = 0; j < 4; ++j) {
                float acc = __fmul_rn(A[i*4+0], L[0*4+j]);
                acc = __fmaf_rn(A[i*4+1], L[1*4+j], acc);
                acc = __fmaf_rn(A[i*4+2], L[2*4+j], acc);
                M1[i*4+j] = acc;
            }
        }
        #pragma unroll
        for (int i = 0; i < 3; ++i) {
            #pragma unroll
            for (int j = 0; j < 4; ++j) {
                float acc = __fmul_rn(M1[i*4+0], lam[0*4+j]);
                acc = __fmaf_rn(M1[i*4+1], lam[1*4+j], acc);
                acc = __fmaf_rn(M1[i*4+2], lam[2*4+j], acc);
                acc = __fmaf_rn(M1[i*4+3], lam[3*4+j], acc);
                pa[n*12 + i*4 + j] = acc;
            }
        }
        pa[72 + n*2 + 0] = A[0*4 + 3];
        pa[72 + n*2 + 1] = A[1*4 + 3];
    } else {
        // fold BN into conv weights, row-major per output: w2n[o*256 + c]
        int o = bid - 1;                 // 0..79
        float inv = 1.0f / sqrtf(var[o] + 1e-5f);
        float sc = __fmul_rn(inv, gamma[o]);
        w2n[o * C_IN + t] = __fmul_rn(conv_w[o * C_IN + t], sc);
        if (t == 0) {
            bias2[o] = __fadd_rn(__fmul_rn(__fsub_rn(conv_b[o], mean[o]), sc), beta[o]);
        }
    }
}

// ---------------- kernel 2: feat2[pos][o] = sum_c w2[o][c]*feat[c][pos] ----------------
// 264 blocks x 512 threads; block tile = 64 pos x 80 out, SPLIT-K over channels:
// waves 0-3 (half=0) accumulate ch {0-31,64-95,128-159,192-223}, waves 4-7 the rest.
// All staging via global_load_lds (zero VGPR). 2 waves/SIMD for latency hiding.
#define CK 64
#define WPAD 260   // row stride 1040 B: 16B-aligned, og-groups land on distinct banks
__global__ __launch_bounds__(512, 2) void k_conv(const float* __restrict__ feat,
                                                 const float* __restrict__ w2n,
                                                 float* __restrict__ feat2) {
    __shared__ float wtile[C_OUT][WPAD];     // 83,200 B: all 256 ch resident
    __shared__ float ftile[2][CK][64];       // 32,768 B double buffer (linear: gload_lds)
    __shared__ float s_out[2][64][81];       // 41,472 B: per-half partials
    int b = blockIdx.x;                      // 264 = 6 cams * 44 tiles
    int n = b / 44;
    int vu0 = (b % 44) * 64;
    int t = threadIdx.x;
    int w = t >> 6, lane = t & 63;           // wave 0..7
    int tt = t & 255, pg = tt & 15, og = tt >> 4;   // both halves cover same 64x80 tile
    int half = w >> 2;                       // channel-split group
    const float* feat_n = feat + (size_t)n * C_IN * POS_PER_CAM + vu0;

    // ---- weight stage via gload_lds: row r = 256 floats = exactly 64 lanes x 16B ----
    #pragma unroll
    for (int i = 0; i < 10; ++i) {
        int r = w * 10 + i;                  // 8 waves x 10 rows = 80
        gload_lds16(w2n + r * C_IN + lane * 4, &wtile[r][0]);
    }
    // ---- feat chunk 0: wave w stages chunk-local ch [w*8, w*8+8) ----
    int ch_a = w * 8 + (lane >> 4);
    int p4   = (lane & 15) << 2;
    const float* gsrc = feat_n + (size_t)ch_a * POS_PER_CAM + p4;
    gload_lds16(gsrc, &ftile[0][w * 8][0]);
    gload_lds16(gsrc + (size_t)4 * POS_PER_CAM, &ftile[0][w * 8 + 4][0]);
    __syncthreads();   // drains all waves' vmcnt -> weights + chunk 0 ready

    float acc[4][5];
    #pragma unroll
    for (int p = 0; p < 4; ++p)
        #pragma unroll
        for (int k = 0; k < 5; ++k) acc[p][k] = 0.0f;

    #pragma unroll 1
    for (int chunk = 0; chunk < C_IN / CK; ++chunk) {
        int cb = chunk & 1;
        // issue next chunk's loads (complete under compute, drained by barrier)
        if (chunk < C_IN / CK - 1) {
            const float* g2 = gsrc + (size_t)(chunk + 1) * CK * POS_PER_CAM;
            gload_lds16(g2, &ftile[cb ^ 1][w * 8][0]);
            gload_lds16(g2 + (size_t)4 * POS_PER_CAM, &ftile[cb ^ 1][w * 8 + 4][0]);
        }
        // compute this half's 32 channels of the chunk
        int c0 = chunk * CK + half * 32;     // global channel base (wtile index)
        #pragma unroll
        for (int q = 0; q < 8; ++q) {
            float4 fp[4], wv[5];
            #pragma unroll
            for (int j = 0; j < 4; ++j)
                fp[j] = *reinterpret_cast<const float4*>(&ftile[cb][half*32 + q*4 + j][pg*4]);
            #pragma unroll
            for (int k = 0; k < 5; ++k)
                wv[k] = *reinterpret_cast<const float4*>(&wtile[og*5+k][c0 + q*4]);
            #pragma unroll
            for (int j = 0; j < 4; ++j) {          // channel ascending within this half
                #pragma unroll
                for (int k = 0; k < 5; ++k) {
                    float wgt = (&wv[k].x)[j];
                    acc[0][k] = __fmaf_rn(wgt, (&fp[j].x)[0], acc[0][k]);
                    acc[1][k] = __fmaf_rn(wgt, (&fp[j].x)[1], acc[1][k]);
                    acc[2][k] = __fmaf_rn(wgt, (&fp[j].x)[2], acc[2][k]);
                    acc[3][k] = __fmaf_rn(wgt, (&fp[j].x)[3], acc[3][k]);
                }
            }
        }
        __syncthreads();
    }

    // ---- merge halves + coalesced store ----
    #pragma unroll
    for (int p = 0; p < 4; ++p)
        #pragma unroll
        for (int k = 0; k < 5; ++k)
            s_out[half][pg*4 + p][og*5 + k] = acc[p][k];
    __syncthreads();
    float* gdst = feat2 + ((size_t)n * POS_PER_CAM + vu0) * C_OUT;
    #pragma unroll
    for (int it = 0; it < 10; ++it) {
        int f = it * 512 + t;                // 5120 floats
        int pos = f / 80, o = f - pos * 80;
        gdst[f] = __fadd_rn(s_out[0][pos][o], s_out[1][pos][o]);
    }
}

// ---------------- kernel 3: backproject + weighted z-sum + bias + relu ----------------
__global__ __launch_bounds__(256) void k_main(const float* __restrict__ feat2,
                                              const float* __restrict__ pa_g,
                                              const float* __restrict__ bias_g,
                                              const float* __restrict__ points,
                                              float* __restrict__ out) {
    __shared__ float s_pa[84];
    __shared__ float s_bias[C_OUT];
    __shared__ int   s_base[64];
    __shared__ float s_w[64];
    __shared__ float s_y[16 * 81];   // stride 81: conflict-free transpose
    int t = threadIdx.x;
    int col0 = blockIdx.x * 16;

    if (t < 84) s_pa[t] = pa_g[t];
    else if (t >= 128 && t < 128 + C_OUT) s_bias[t - 128] = bias_g[t - 128];
    __syncthreads();

    // phase 1: per (column, z) camera selection — fp32 mimicking numpy op order
    if (t < 64) {
        int cl = t >> 2, z = t & 3;
        int col = col0 + cl;
        int ix = col / NYG, iy = col % NYG;
        float x  = (float)ix * 0.5f - 50.0f;   // exact dyadic
        float y  = (float)iy * 0.5f - 50.0f;
        float zc = (float)z  * 1.5f - 4.0f;
        int sel_base = 0;
        bool any = false;
        #pragma unroll
        for (int n = 0; n < N_CAM; ++n) {
            const float* P = s_pa + n * 12;
            // sequential non-fused mul/add: matches np.einsum (no FMA, j ascending)
            float px = __fadd_rn(__fadd_rn(__fadd_rn(__fmul_rn(P[0], x), __fmul_rn(P[1], y)), __fmul_rn(P[2], zc)), P[3]);
            float py = __fadd_rn(__fadd_rn(__fadd_rn(__fmul_rn(P[4], x), __fmul_rn(P[5], y)), __fmul_rn(P[6], zc)), P[7]);
            float pz = __fadd_rn(__fadd_rn(__fadd_rn(__fmul_rn(P[8], x), __fmul_rn(P[9], y)), __fmul_rn(P[10], zc)), P[11]);
            float Z = pz;
            float Zs = (fabsf(Z) > 1e-6f) ? Z : 1e-6f;
            float u = __fadd_rn(px / Zs, s_pa[72 + n*2 + 0]);
            float v = __fadd_rn(py / Zs, s_pa[72 + n*2 + 1]);
            float uf = rintf(__fmul_rn(u, 0.125f));   // u/8 exact; rintf = half-even = np.round
            float vf = rintf(__fmul_rn(v, 0.125f));
            int ui = (int)uf, vi = (int)vf;           // saturating cvt; out-of-range stays invalid
            bool val = (ui >= 0) & (vi >= 0) & (ui < FW) & (vi < FH) & (Z > 0.0f);
            if (val) { sel_base = ((n * FH + vi) * FW + ui) * C_OUT; any = true; }  // last valid wins
        }
        float w = 0.0f;
        if (any) w = points[z * S_SPATIAL + col];
        else sel_base = 0;
        s_base[t] = sel_base;
        s_w[t] = w;
    }
    __syncthreads();

    // phase 2: gather 80 contiguous floats per (col,z), weighted z-sum, bias, relu
    #pragma unroll
    for (int it = 0; it < 5; ++it) {
        int idx = it * 256 + t;            // 16 cols * 80 outs = 1280
        int cl = idx / 80, o = idx - cl * 80;
        float acc =            __fmul_rn(s_w[cl*4+0], feat2[s_base[cl*4+0] + o]);
        acc = __fadd_rn(acc, __fmul_rn(s_w[cl*4+1], feat2[s_base[cl*4+1] + o]));
        acc = __fadd_rn(acc, __fmul_rn(s_w[cl*4+2], feat2[s_base[cl*4+2] + o]));
        acc = __fadd_rn(acc, __fmul_rn(s_w[cl*4+3], feat2[s_base[cl*4+3] + o]));
        float yv = fmaxf(__fadd_rn(acc, s_bias[o]), 0.0f);
        s_y[cl * 81 + o] = yv;
    }
    __syncthreads();

    // phase 3: transposed write — coalesced 16-float segments per o
    #pragma unroll
    for (int it = 0; it < 5; ++it) {
        int idx = it * 256 + t;
        int o = idx >> 4, cl = idx & 15;
        out[o * S_SPATIAL + col0 + cl] = s_y[cl * 81 + o];
    }
}

extern "C" void kernel_launch(void* const* d_in, const int* in_sizes, int n_in,
                              void* d_out, int out_size, void* d_ws, size_t ws_size,
                              hipStream_t stream) {
    const float* feat   = (const float*)d_in[0];   // (1,6,256,32,88)
    const float* points = (const float*)d_in[1];   // (1,4,200,200)
    const float* l2i    = (const float*)d_in[5];   // lidar2image (1,6,4,4)
    const float* iam    = (const float*)d_in[8];   // img_aug_matrix (1,6,4,4)
    const float* lam    = (const float*)d_in[9];   // lidar_aug_matrix (1,4,4)
    const float* conv_w = (const float*)d_in[11];  // (80,256)
    const float* conv_b = (const float*)d_in[12];
    const float* gamma  = (const float*)d_in[13];
    const float* beta   = (const float*)d_in[14];
    const float* mean   = (const float*)d_in[15];
    const float* var    = (const float*)d_in[16];

    float* ws    = (float*)d_ws;
    float* pa    = ws + WS_PA;
    float* bias2 = ws + WS_BIAS;
    float* w2n   = ws + WS_W2N;
    float* feat2 = ws + WS_FEAT2;
    float* out   = (float*)d_out;

    hipLaunchKernelGGL(k_prep, dim3(1 + C_OUT), dim3(256), 0, stream,
                       iam, lam, l2i, conv_w, conv_b, gamma, beta, mean, var,
                       pa, w2n, bias2);
    hipLaunchKernelGGL(k_conv, dim3(NPOS / 64), dim3(512), 0, stream, feat, w2n, feat2);
    hipLaunchKernelGGL(k_main, dim3(S_SPATIAL / 16), dim3(256), 0, stream,
                       feat2, pa, bias2, points, out);
}

// Round 6
// 30.351 us; speedup vs baseline: 3.4194x; 1.4570x over previous
//
#include <hip/hip_runtime.h>
#include <math.h>

typedef __attribute__((ext_vector_type(8))) short bf16x8;
typedef __attribute__((ext_vector_type(4))) float f32x4;

#define N_CAM 6
#define C_IN 256
#define C_OUT 80
#define FH 32
#define FW 88
#define NXG 200
#define NYG 200
#define S_SPATIAL (NXG*NYG)        // 40000
#define POS_PER_CAM (FH*FW)        // 2816
#define NPOS (N_CAM*POS_PER_CAM)   // 16896

// ws layout (in floats)
#define WS_PA     0      // 84 floats: proj[6][12] + aug[6][2]
#define WS_BIAS   128    // 80 floats
#define WS_WF     256    // w2 B-fragment order, bf16: 40*64*16B = 40 KiB = 10240 floats
#define WS_FEAT2B 10496  // feat2 bf16 [pos][80]: 1,351,680 ushorts = 675,840 floats
// feat_t (A-fragment-order bf16, 8.65 MB) lives in d_out scratch until k_main overwrites it.

__device__ __forceinline__ unsigned short f2bf(float f) {   // RTN-even fp32->bf16
    unsigned u = __builtin_bit_cast(unsigned, f);
    u += 0x7fffu + ((u >> 16) & 1u);
    return (unsigned short)(u >> 16);
}
__device__ __forceinline__ float bf2f(unsigned short u) {
    return __builtin_bit_cast(float, ((unsigned)u) << 16);
}

// ---------------- kernel 1: matrices + bias + B-fragment weights ----------------
// grid 41 x 128. bid 0: matrices (t<6) + bias (48<=t<128). bid 1..40: fragment fi=bid-1.
__global__ __launch_bounds__(128) void k_prep(const float* __restrict__ iam,
                       const float* __restrict__ lam,
                       const float* __restrict__ l2i,
                       const float* __restrict__ conv_w, const float* __restrict__ conv_b,
                       const float* __restrict__ gamma, const float* __restrict__ beta,
                       const float* __restrict__ mean, const float* __restrict__ var,
                       float* __restrict__ pa, uint4* __restrict__ wf,
                       float* __restrict__ bias2) {
    int bid = blockIdx.x;
    int t = threadIdx.x;
    if (bid == 0) {
        if (t < N_CAM) {
            int n = t;
            const float* A = iam + n * 16;   // img_aug_matrix (last col zeroed for proj)
            const float* L = l2i + n * 16;   // lidar2image
            float M1[12];
            #pragma unroll
            for (int i = 0; i < 3; ++i)
                #pragma unroll
                for (int j = 0; j < 4; ++j) {
                    float acc = __fmul_rn(A[i*4+0], L[0*4+j]);
                    acc = __fmaf_rn(A[i*4+1], L[1*4+j], acc);
                    acc = __fmaf_rn(A[i*4+2], L[2*4+j], acc);
                    M1[i*4+j] = acc;
                }
            #pragma unroll
            for (int i = 0; i < 3; ++i)
                #pragma unroll
                for (int j = 0; j < 4; ++j) {
                    float acc = __fmul_rn(M1[i*4+0], lam[0*4+j]);
                    acc = __fmaf_rn(M1[i*4+1], lam[1*4+j], acc);
                    acc = __fmaf_rn(M1[i*4+2], lam[2*4+j], acc);
                    acc = __fmaf_rn(M1[i*4+3], lam[3*4+j], acc);
                    pa[n*12 + i*4 + j] = acc;
                }
            pa[72 + n*2 + 0] = A[0*4 + 3];
            pa[72 + n*2 + 1] = A[1*4 + 3];
        } else if (t >= 48) {
            int o = t - 48;                  // 0..79
            float inv = 1.0f / sqrtf(var[o] + 1e-5f);
            float sc = __fmul_rn(inv, gamma[o]);
            bias2[o] = __fadd_rn(__fmul_rn(__fsub_rn(conv_b[o], mean[o]), sc), beta[o]);
        }
        return;
    }
    if (t >= 64) return;
    // B-fragment fi: lane l supplies B[k=ks*32+(l>>4)*8+j][n=out=nt*16+(l&15)], j=0..7
    int fi = bid - 1;                        // 0..39
    int nt = fi >> 3, ks = fi & 7;
    int o  = nt * 16 + (t & 15);
    int cb = ks * 32 + (t >> 4) * 8;
    float inv = 1.0f / sqrtf(var[o] + 1e-5f);
    float sc = __fmul_rn(inv, gamma[o]);
    unsigned short e[8];
    #pragma unroll
    for (int j = 0; j < 8; ++j)
        e[j] = f2bf(__fmul_rn(conv_w[o * C_IN + cb + j], sc));
    uint4 u;
    u.x = e[0] | ((unsigned)e[1] << 16);
    u.y = e[2] | ((unsigned)e[3] << 16);
    u.z = e[4] | ((unsigned)e[5] << 16);
    u.w = e[6] | ((unsigned)e[7] << 16);
    wf[fi * 64 + t] = u;
}

// ---------------- kernel 2: feat fp32 [c][pos] -> bf16 A-fragment-order global ----------------
// Block = 64 pos x 256 ch. A-frag chunk f (16B): lane l holds A[pos=(l&15)][ch 8 consecutive].
__global__ __launch_bounds__(256) void k_trans(const float* __restrict__ feat,
                                               uint4* __restrict__ ft) {
    __shared__ uint4 sfo[2048];              // 32 KiB, fragment-ordered
    int b = blockIdx.x, t = threadIdx.x;     // 264 blocks
    int n = b / 44, p0 = (b % 44) * 64;
    const float* fn = feat + (size_t)n * C_IN * POS_PER_CAM + p0;
    uint2* sfo2 = reinterpret_cast<uint2*>(sfo);
    #pragma unroll
    for (int i = 0; i < 16; ++i) {
        int task = i * 256 + t;              // 64 pos x 64 ch-quads
        int pl = task & 63, cg = task >> 6;
        int c0 = cg * 4;
        float v0 = fn[(c0+0) * POS_PER_CAM + pl];   // coalesced: lanes = consecutive pos
        float v1 = fn[(c0+1) * POS_PER_CAM + pl];
        float v2 = fn[(c0+2) * POS_PER_CAM + pl];
        float v3 = fn[(c0+3) * POS_PER_CAM + pl];
        unsigned lo = f2bf(v0) | ((unsigned)f2bf(v1) << 16);
        unsigned hi = f2bf(v2) | ((unsigned)f2bf(v3) << 16);
        int ksp = c0 >> 5;                   // k-step 0..7
        int q   = (c0 & 31) >> 3;            // k-subgroup 0..3 -> lane_f bits 4,5
        int lf  = (pl & 15) + (q << 4);      // fragment lane
        int f   = ((pl >> 4) * 8 + ksp) * 64 + lf;   // 16B chunk index (mtile-major)
        sfo2[f * 2 + (cg & 1)] = make_uint2(lo, hi);
    }
    __syncthreads();
    uint4* dst = ft + (size_t)b * 2048;      // block's 32 KiB contiguous
    #pragma unroll
    for (int i = 0; i < 8; ++i)
        dst[i * 256 + t] = sfo[i * 256 + t];
}

// ---------------- kernel 3: feat2 = feat_t x w2^T via MFMA (no LDS, no barriers) ----------------
// 264 blocks x 256 thr (4 waves). Wave = 16-pos strip: 8 A-frags (reg) x 5 N-tiles x 8 K-steps.
__global__ __launch_bounds__(256) void k_conv(const bf16x8* __restrict__ ft,
                                              const bf16x8* __restrict__ wf,
                                              unsigned short* __restrict__ feat2b) {
    int b = blockIdx.x, t = threadIdx.x;
    int wv = t >> 6, l = t & 63;
    int gpt = b * 4 + wv;                    // global 16-pos tile
    bf16x8 a[8];
    #pragma unroll
    for (int ks = 0; ks < 8; ++ks)
        a[ks] = ft[(gpt * 8 + ks) * 64 + l];
    int posb = b * 64 + wv * 16 + ((l >> 4) << 2);   // D row = (l>>4)*4 + r
    #pragma unroll
    for (int nt = 0; nt < 5; ++nt) {
        f32x4 acc = {0.f, 0.f, 0.f, 0.f};
        #pragma unroll
        for (int ks = 0; ks < 8; ++ks) {     // K ascending
            bf16x8 bb = wf[(nt * 8 + ks) * 64 + l];
            acc = __builtin_amdgcn_mfma_f32_16x16x32_bf16(a[ks], bb, acc, 0, 0, 0);
        }
        #pragma unroll
        for (int r = 0; r < 4; ++r)
            feat2b[(size_t)(posb + r) * C_OUT + nt * 16 + (l & 15)] = f2bf(acc[r]);
    }
}

// ---------------- kernel 4: backproject + weighted z-sum + bias + relu ----------------
__global__ __launch_bounds__(256) void k_main(const unsigned short* __restrict__ feat2b,
                                              const float* __restrict__ pa_g,
                                              const float* __restrict__ bias_g,
                                              const float* __restrict__ points,
                                              float* __restrict__ out) {
    __shared__ float s_pa[84];
    __shared__ float s_bias[C_OUT];
    __shared__ int   s_base[64];
    __shared__ float s_w[64];
    __shared__ float s_y[16 * 81];   // stride 81: conflict-free transpose
    int t = threadIdx.x;
    int col0 = blockIdx.x * 16;

    if (t < 84) s_pa[t] = pa_g[t];
    else if (t >= 128 && t < 128 + C_OUT) s_bias[t - 128] = bias_g[t - 128];
    __syncthreads();

    // phase 1: per (column, z) camera selection — fp32 mimicking numpy op order
    if (t < 64) {
        int cl = t >> 2, z = t & 3;
        int col = col0 + cl;
        int ix = col / NYG, iy = col % NYG;
        float x  = (float)ix * 0.5f - 50.0f;   // exact dyadic
        float y  = (float)iy * 0.5f - 50.0f;
        float zc = (float)z  * 1.5f - 4.0f;
        int sel_base = 0;
        bool any = false;
        #pragma unroll
        for (int n = 0; n < N_CAM; ++n) {
            const float* P = s_pa + n * 12;
            // sequential non-fused mul/add: matches np.einsum (no FMA, j ascending)
            float px = __fadd_rn(__fadd_rn(__fadd_rn(__fmul_rn(P[0], x), __fmul_rn(P[1], y)), __fmul_rn(P[2], zc)), P[3]);
            float py = __fadd_rn(__fadd_rn(__fadd_rn(__fmul_rn(P[4], x), __fmul_rn(P[5], y)), __fmul_rn(P[6], zc)), P[7]);
            float pz = __fadd_rn(__fadd_rn(__fadd_rn(__fmul_rn(P[8], x), __fmul_rn(P[9], y)), __fmul_rn(P[10], zc)), P[11]);
            float Z = pz;
            float Zs = (fabsf(Z) > 1e-6f) ? Z : 1e-6f;
            float u = __fadd_rn(px / Zs, s_pa[72 + n*2 + 0]);
            float v = __fadd_rn(py / Zs, s_pa[72 + n*2 + 1]);
            float uf = rintf(__fmul_rn(u, 0.125f));   // u/8 exact; rintf = half-even = np.round
            float vf = rintf(__fmul_rn(v, 0.125f));
            int ui = (int)uf, vi = (int)vf;           // saturating cvt; out-of-range stays invalid
            bool val = (ui >= 0) & (vi >= 0) & (ui < FW) & (vi < FH) & (Z > 0.0f);
            if (val) { sel_base = ((n * FH + vi) * FW + ui) * C_OUT; any = true; }  // last valid wins
        }
        float w = 0.0f;
        if (any) w = points[z * S_SPATIAL + col];
        else sel_base = 0;
        s_base[t] = sel_base;
        s_w[t] = w;
    }
    __syncthreads();

    // phase 2: gather 80 contiguous bf16 per (col,z), weighted z-sum, bias, relu
    #pragma unroll
    for (int it = 0; it < 5; ++it) {
        int idx = it * 256 + t;            // 16 cols * 80 outs = 1280
        int cl = idx / 80, o = idx - cl * 80;
        float acc =            __fmul_rn(s_w[cl*4+0], bf2f(feat2b[s_base[cl*4+0] + o]));
        acc = __fadd_rn(acc, __fmul_rn(s_w[cl*4+1], bf2f(feat2b[s_base[cl*4+1] + o])));
        acc = __fadd_rn(acc, __fmul_rn(s_w[cl*4+2], bf2f(feat2b[s_base[cl*4+2] + o])));
        acc = __fadd_rn(acc, __fmul_rn(s_w[cl*4+3], bf2f(feat2b[s_base[cl*4+3] + o])));
        float yv = fmaxf(__fadd_rn(acc, s_bias[o]), 0.0f);
        s_y[cl * 81 + o] = yv;
    }
    __syncthreads();

    // phase 3: transposed write — coalesced 16-float segments per o
    #pragma unroll
    for (int it = 0; it < 5; ++it) {
        int idx = it * 256 + t;
        int o = idx >> 4, cl = idx & 15;
        out[o * S_SPATIAL + col0 + cl] = s_y[cl * 81 + o];
    }
}

extern "C" void kernel_launch(void* const* d_in, const int* in_sizes, int n_in,
                              void* d_out, int out_size, void* d_ws, size_t ws_size,
                              hipStream_t stream) {
    const float* feat   = (const float*)d_in[0];   // (1,6,256,32,88)
    const float* points = (const float*)d_in[1];   // (1,4,200,200)
    const float* l2i    = (const float*)d_in[5];   // lidar2image (1,6,4,4)
    const float* iam    = (const float*)d_in[8];   // img_aug_matrix (1,6,4,4)
    const float* lam    = (const float*)d_in[9];   // lidar_aug_matrix (1,4,4)
    const float* conv_w = (const float*)d_in[11];  // (80,256)
    const float* conv_b = (const float*)d_in[12];
    const float* gamma  = (const float*)d_in[13];
    const float* beta   = (const float*)d_in[14];
    const float* mean   = (const float*)d_in[15];
    const float* var    = (const float*)d_in[16];

    float* ws     = (float*)d_ws;
    float* pa     = ws + WS_PA;
    float* bias2  = ws + WS_BIAS;
    uint4* wf     = (uint4*)(ws + WS_WF);
    unsigned short* feat2b = (unsigned short*)(ws + WS_FEAT2B);
    float* out    = (float*)d_out;
    // feat_t (bf16, A-fragment order, 8.65 MB) borrows d_out as scratch;
    // it is fully consumed by k_conv before k_main overwrites every element of d_out.
    uint4* ft     = (uint4*)d_out;

    hipLaunchKernelGGL(k_prep, dim3(41), dim3(128), 0, stream,
                       iam, lam, l2i, conv_w, conv_b, gamma, beta, mean, var,
                       pa, wf, bias2);
    hipLaunchKernelGGL(k_trans, dim3(NPOS / 64), dim3(256), 0, stream, feat, ft);
    hipLaunchKernelGGL(k_conv, dim3(NPOS / 64), dim3(256), 0, stream,
                       (const bf16x8*)ft, (const bf16x8*)wf, feat2b);
    hipLaunchKernelGGL(k_main, dim3(S_SPATIAL / 16), dim3(256), 0, stream,
                       feat2b, pa, bias2, points, out);
}

// Round 7
// 25.116 us; speedup vs baseline: 4.1320x; 1.2084x over previous
//
#include <hip/hip_runtime.h>
#include <math.h>

typedef __attribute__((ext_vector_type(8))) short bf16x8;
typedef __attribute__((ext_vector_type(4))) float f32x4;

#define N_CAM 6
#define C_IN 256
#define C_OUT 80
#define FH 32
#define FW 88
#define NXG 200
#define NYG 200
#define S_SPATIAL (NXG*NYG)        // 40000
#define POS_PER_CAM (FH*FW)        // 2816
#define NPOS (N_CAM*POS_PER_CAM)   // 16896

// ws layout (in floats)
#define WS_PA     0      // 84 floats: proj[6][12] + aug[6][2]
#define WS_BIAS   128    // 80 floats
#define WS_WF     256    // w2 B-fragment order, bf16: 40 frags * 64 lanes * 16B = 10240 floats
#define WS_FEAT2B 10496  // feat2 bf16 [pos][80]: 1,351,680 ushorts

__device__ __forceinline__ unsigned short f2bf(float f) {   // RTN-even fp32->bf16
    unsigned u = __builtin_bit_cast(unsigned, f);
    u += 0x7fffu + ((u >> 16) & 1u);
    return (unsigned short)(u >> 16);
}
__device__ __forceinline__ float bf2f(unsigned short u) {
    return __builtin_bit_cast(float, ((unsigned)u) << 16);
}

// ---------------- kernel 1: matrices + bias + B-fragment weights ----------------
// grid 41 x 128. bid 0: matrices (t<6) + bias (48<=t<128). bid 1..40: fragment fi=bid-1.
__global__ __launch_bounds__(128) void k_prep(const float* __restrict__ iam,
                       const float* __restrict__ lam,
                       const float* __restrict__ l2i,
                       const float* __restrict__ conv_w, const float* __restrict__ conv_b,
                       const float* __restrict__ gamma, const float* __restrict__ beta,
                       const float* __restrict__ mean, const float* __restrict__ var,
                       float* __restrict__ pa, uint4* __restrict__ wf,
                       float* __restrict__ bias2) {
    int bid = blockIdx.x;
    int t = threadIdx.x;
    if (bid == 0) {
        if (t < N_CAM) {
            int n = t;
            const float* A = iam + n * 16;   // img_aug_matrix (last col zeroed for proj)
            const float* L = l2i + n * 16;   // lidar2image
            float M1[12];
            #pragma unroll
            for (int i = 0; i < 3; ++i)
                #pragma unroll
                for (int j = 0; j < 4; ++j) {
                    float acc = __fmul_rn(A[i*4+0], L[0*4+j]);
                    acc = __fmaf_rn(A[i*4+1], L[1*4+j], acc);
                    acc = __fmaf_rn(A[i*4+2], L[2*4+j], acc);
                    M1[i*4+j] = acc;
                }
            #pragma unroll
            for (int i = 0; i < 3; ++i)
                #pragma unroll
                for (int j = 0; j < 4; ++j) {
                    float acc = __fmul_rn(M1[i*4+0], lam[0*4+j]);
                    acc = __fmaf_rn(M1[i*4+1], lam[1*4+j], acc);
                    acc = __fmaf_rn(M1[i*4+2], lam[2*4+j], acc);
                    acc = __fmaf_rn(M1[i*4+3], lam[3*4+j], acc);
                    pa[n*12 + i*4 + j] = acc;
                }
            pa[72 + n*2 + 0] = A[0*4 + 3];
            pa[72 + n*2 + 1] = A[1*4 + 3];
        } else if (t >= 48) {
            int o = t - 48;                  // 0..79
            float inv = 1.0f / sqrtf(var[o] + 1e-5f);
            float sc = __fmul_rn(inv, gamma[o]);
            bias2[o] = __fadd_rn(__fmul_rn(__fsub_rn(conv_b[o], mean[o]), sc), beta[o]);
        }
        return;
    }
    if (t >= 64) return;
    // B-fragment fi: lane l supplies B[k=ks*32+(l>>4)*8+j][n=out=nt*16+(l&15)], j=0..7
    int fi = bid - 1;                        // 0..39
    int nt = fi >> 3, ks = fi & 7;
    int o  = nt * 16 + (t & 15);
    int cb = ks * 32 + (t >> 4) * 8;
    float inv = 1.0f / sqrtf(var[o] + 1e-5f);
    float sc = __fmul_rn(inv, gamma[o]);
    unsigned short e[8];
    #pragma unroll
    for (int j = 0; j < 8; ++j)
        e[j] = f2bf(__fmul_rn(conv_w[o * C_IN + cb + j], sc));
    uint4 u;
    u.x = e[0] | ((unsigned)e[1] << 16);
    u.y = e[2] | ((unsigned)e[3] << 16);
    u.z = e[4] | ((unsigned)e[5] << 16);
    u.w = e[6] | ((unsigned)e[7] << 16);
    wf[fi * 64 + t] = u;
}

// ---------------- kernel 2: fused convert/transpose + MFMA ----------------
// 264 blocks x 256 thr. Stage 64pos x 256ch as bf16 A-fragments in LDS, then
// wave wv: 8 ds_read_b128 A-frags + 40 global B-frags -> 40 MFMA -> feat2b.
__global__ __launch_bounds__(256) void k_fconv(const float* __restrict__ feat,
                                               const bf16x8* __restrict__ wf,
                                               unsigned short* __restrict__ feat2b) {
    __shared__ uint4 sfo[2048];              // 32 KiB, fragment-ordered bf16 tile
    int b = blockIdx.x, t = threadIdx.x;     // 264 = 6 cams * 44 tiles
    int n = b / 44, p0 = (b % 44) * 64;
    const float* fn = feat + (size_t)n * C_IN * POS_PER_CAM + p0;
    uint2* sfo2 = reinterpret_cast<uint2*>(sfo);
    #pragma unroll
    for (int i = 0; i < 16; ++i) {
        int task = i * 256 + t;              // 64 pos x 64 ch-quads
        int pl = task & 63, cg = task >> 6;
        int c0 = cg * 4;
        float v0 = fn[(c0+0) * POS_PER_CAM + pl];   // coalesced: lanes = consecutive pos
        float v1 = fn[(c0+1) * POS_PER_CAM + pl];
        float v2 = fn[(c0+2) * POS_PER_CAM + pl];
        float v3 = fn[(c0+3) * POS_PER_CAM + pl];
        unsigned lo = f2bf(v0) | ((unsigned)f2bf(v1) << 16);
        unsigned hi = f2bf(v2) | ((unsigned)f2bf(v3) << 16);
        int ksp = c0 >> 5;                   // k-step 0..7
        int q   = (c0 & 31) >> 3;            // k-subgroup -> fragment-lane bits 4,5
        int lf  = (pl & 15) + (q << 4);      // fragment lane
        int f   = ((pl >> 4) * 8 + ksp) * 64 + lf;   // 16B chunk index (mtile-major)
        sfo2[f * 2 + (cg & 1)] = make_uint2(lo, hi);
    }
    __syncthreads();

    int wv = t >> 6, l = t & 63;
    const bf16x8* sfrag = reinterpret_cast<const bf16x8*>(sfo);
    bf16x8 a[8];
    #pragma unroll
    for (int ks = 0; ks < 8; ++ks)
        a[ks] = sfrag[(wv * 8 + ks) * 64 + l];
    int posb = b * 64 + wv * 16 + ((l >> 4) << 2);   // D row = (l>>4)*4 + r
    #pragma unroll
    for (int nt = 0; nt < 5; ++nt) {
        f32x4 acc = {0.f, 0.f, 0.f, 0.f};
        #pragma unroll
        for (int ks = 0; ks < 8; ++ks) {     // K ascending
            bf16x8 bb = wf[(nt * 8 + ks) * 64 + l];
            acc = __builtin_amdgcn_mfma_f32_16x16x32_bf16(a[ks], bb, acc, 0, 0, 0);
        }
        #pragma unroll
        for (int r = 0; r < 4; ++r)
            feat2b[(size_t)(posb + r) * C_OUT + nt * 16 + (l & 15)] = f2bf(acc[r]);
    }
}

// ---------------- kernel 3: backproject + weighted z-sum + bias + relu ----------------
// 625 blocks x 256 thr; 64 BEV columns per block. Phase 1 uses ALL threads
// (t = z*64+cl -> coalesced points read); phase 3 writes 256B segments.
__global__ __launch_bounds__(256) void k_main(const unsigned short* __restrict__ feat2b,
                                              const float* __restrict__ pa_g,
                                              const float* __restrict__ bias_g,
                                              const float* __restrict__ points,
                                              float* __restrict__ out) {
    __shared__ float s_pa[84];
    __shared__ float s_bias[C_OUT];
    __shared__ int   s_base[256];
    __shared__ float s_w[256];
    __shared__ float s_y[64 * 81];   // stride 81: conflict-free transpose
    int t = threadIdx.x;
    int col0 = blockIdx.x * 64;

    if (t < 84) s_pa[t] = pa_g[t];
    else if (t >= 128 && t < 128 + C_OUT) s_bias[t - 128] = bias_g[t - 128];
    __syncthreads();

    // phase 1: per (column, z) camera selection — fp32 mimicking numpy op order
    {
        int cl = t & 63, z = t >> 6;
        int col = col0 + cl;
        int ix = col / NYG, iy = col % NYG;
        float x  = (float)ix * 0.5f - 50.0f;   // exact dyadic
        float y  = (float)iy * 0.5f - 50.0f;
        float zc = (float)z  * 1.5f - 4.0f;
        int sel_base = 0;
        bool any = false;
        #pragma unroll
        for (int n = 0; n < N_CAM; ++n) {
            const float* P = s_pa + n * 12;
            // sequential non-fused mul/add: matches np.einsum (no FMA, j ascending)
            float px = __fadd_rn(__fadd_rn(__fadd_rn(__fmul_rn(P[0], x), __fmul_rn(P[1], y)), __fmul_rn(P[2], zc)), P[3]);
            float py = __fadd_rn(__fadd_rn(__fadd_rn(__fmul_rn(P[4], x), __fmul_rn(P[5], y)), __fmul_rn(P[6], zc)), P[7]);
            float pz = __fadd_rn(__fadd_rn(__fadd_rn(__fmul_rn(P[8], x), __fmul_rn(P[9], y)), __fmul_rn(P[10], zc)), P[11]);
            float Z = pz;
            float Zs = (fabsf(Z) > 1e-6f) ? Z : 1e-6f;
            float u = __fadd_rn(px / Zs, s_pa[72 + n*2 + 0]);
            float v = __fadd_rn(py / Zs, s_pa[72 + n*2 + 1]);
            float uf = rintf(__fmul_rn(u, 0.125f));   // u/8 exact; rintf = half-even = np.round
            float vf = rintf(__fmul_rn(v, 0.125f));
            int ui = (int)uf, vi = (int)vf;           // saturating cvt; out-of-range stays invalid
            bool val = (ui >= 0) & (vi >= 0) & (ui < FW) & (vi < FH) & (Z > 0.0f);
            if (val) { sel_base = ((n * FH + vi) * FW + ui) * C_OUT; any = true; }  // last valid wins
        }
        float w = 0.0f;
        if (any) w = points[z * S_SPATIAL + col];   // coalesced: wave = one z plane
        else sel_base = 0;
        s_base[z * 64 + cl] = sel_base;
        s_w[z * 64 + cl] = w;
    }
    __syncthreads();

    // phase 2: gather 80 contiguous bf16 per (col,z), weighted z-sum, bias, relu
    #pragma unroll
    for (int it = 0; it < 20; ++it) {
        int idx = it * 256 + t;            // 64 cols * 80 outs = 5120
        int c = idx / 80, o = idx - c * 80;
        float acc =            __fmul_rn(s_w[0*64+c], bf2f(feat2b[s_base[0*64+c] + o]));
        acc = __fadd_rn(acc, __fmul_rn(s_w[1*64+c], bf2f(feat2b[s_base[1*64+c] + o])));
        acc = __fadd_rn(acc, __fmul_rn(s_w[2*64+c], bf2f(feat2b[s_base[2*64+c] + o])));
        acc = __fadd_rn(acc, __fmul_rn(s_w[3*64+c], bf2f(feat2b[s_base[3*64+c] + o])));
        float yv = fmaxf(__fadd_rn(acc, s_bias[o]), 0.0f);
        s_y[c * 81 + o] = yv;
    }
    __syncthreads();

    // phase 3: transposed write — coalesced 64-float (256B) segments per o
    #pragma unroll
    for (int it = 0; it < 20; ++it) {
        int idx = it * 256 + t;
        int o = idx >> 6, c = idx & 63;
        out[o * S_SPATIAL + col0 + c] = s_y[c * 81 + o];
    }
}

extern "C" void kernel_launch(void* const* d_in, const int* in_sizes, int n_in,
                              void* d_out, int out_size, void* d_ws, size_t ws_size,
                              hipStream_t stream) {
    const float* feat   = (const float*)d_in[0];   // (1,6,256,32,88)
    const float* points = (const float*)d_in[1];   // (1,4,200,200)
    const float* l2i    = (const float*)d_in[5];   // lidar2image (1,6,4,4)
    const float* iam    = (const float*)d_in[8];   // img_aug_matrix (1,6,4,4)
    const float* lam    = (const float*)d_in[9];   // lidar_aug_matrix (1,4,4)
    const float* conv_w = (const float*)d_in[11];  // (80,256)
    const float* conv_b = (const float*)d_in[12];
    const float* gamma  = (const float*)d_in[13];
    const float* beta   = (const float*)d_in[14];
    const float* mean   = (const float*)d_in[15];
    const float* var    = (const float*)d_in[16];

    float* ws     = (float*)d_ws;
    float* pa     = ws + WS_PA;
    float* bias2  = ws + WS_BIAS;
    uint4* wf     = (uint4*)(ws + WS_WF);
    unsigned short* feat2b = (unsigned short*)(ws + WS_FEAT2B);
    float* out    = (float*)d_out;

    hipLaunchKernelGGL(k_prep, dim3(41), dim3(128), 0, stream,
                       iam, lam, l2i, conv_w, conv_b, gamma, beta, mean, var,
                       pa, wf, bias2);
    hipLaunchKernelGGL(k_fconv, dim3(NPOS / 64), dim3(256), 0, stream,
                       feat, (const bf16x8*)wf, feat2b);
    hipLaunchKernelGGL(k_main, dim3(S_SPATIAL / 64), dim3(256), 0, stream,
                       feat2b, pa, bias2, points, out);
}